// Round 5
// baseline (807.462 us; speedup 1.0000x reference)
//
#include <hip/hip_runtime.h>
#include <hip/hip_bf16.h>

#define DFEAT 256

typedef __bf16 bf16x8 __attribute__((ext_vector_type(8)));
typedef __bf16 bf16x4 __attribute__((ext_vector_type(4)));
typedef float  f32x4  __attribute__((ext_vector_type(4)));

// ---------------------------------------------------------------------------
// CSR build: histogram -> hierarchical scan -> cursor scatter (sorted records)
// ---------------------------------------------------------------------------
__global__ void hist_kernel(const int* __restrict__ dst, int nE, int* __restrict__ P) {
    for (int e = blockIdx.x * blockDim.x + threadIdx.x; e < nE; e += gridDim.x * blockDim.x)
        atomicAdd(&P[dst[e] + 1], 1);
}

__global__ __launch_bounds__(256) void scan_block(int* __restrict__ a, int n, int* __restrict__ bsum) {
    __shared__ int wsum[4];
    const int tid = threadIdx.x;
    const int lane = tid & 63, wv = tid >> 6;
    const int idx = blockIdx.x * 2048 + tid * 8;
    int v[8];
    #pragma unroll
    for (int i = 0; i < 8; ++i) v[i] = (idx + i < n) ? a[idx + i] : 0;
    #pragma unroll
    for (int i = 1; i < 8; ++i) v[i] += v[i - 1];
    int tsum = v[7];
    int sc = tsum;
    #pragma unroll
    for (int off = 1; off < 64; off <<= 1) {
        int t = __shfl_up(sc, off);
        if (lane >= off) sc += t;
    }
    if (lane == 63) wsum[wv] = sc;
    __syncthreads();
    int wadd = 0;
    for (int w2 = 0; w2 < wv; ++w2) wadd += wsum[w2];
    int texcl = sc - tsum + wadd;
    #pragma unroll
    for (int i = 0; i < 8; ++i)
        if (idx + i < n) a[idx + i] = v[i] + texcl;
    if (tid == 255) bsum[blockIdx.x] = sc + wadd;
}

__global__ void scan_sums(int* __restrict__ bsum, int nb) {
    int lane = threadIdx.x;
    int v = (lane < nb) ? bsum[lane] : 0;
    #pragma unroll
    for (int off = 1; off < 64; off <<= 1) {
        int t = __shfl_up(v, off);
        if (lane >= off) v += t;
    }
    if (lane < nb) bsum[lane] = v;
}

__global__ __launch_bounds__(256) void scan_add(int* __restrict__ a, int n, const int* __restrict__ bsum) {
    if (blockIdx.x == 0) return;
    int add = bsum[blockIdx.x - 1];
    int idx = blockIdx.x * 2048 + threadIdx.x * 8;
    #pragma unroll
    for (int i = 0; i < 8; ++i)
        if (idx + i < n) a[idx + i] += add;
}

__global__ void copy_int(const int* __restrict__ src, int* __restrict__ dst, int n) {
    for (int i = blockIdx.x * blockDim.x + threadIdx.x; i < n; i += gridDim.x * blockDim.x)
        dst[i] = src[i];
}

__global__ void fill_kernel(const int* __restrict__ dst, const int* __restrict__ src,
                            const float* __restrict__ w, int nE,
                            int* __restrict__ cursor,
                            int* __restrict__ rsrc, float* __restrict__ rw) {
    for (int e = blockIdx.x * blockDim.x + threadIdx.x; e < nE; e += gridDim.x * blockDim.x) {
        int pos = atomicAdd(&cursor[dst[e]], 1);
        rsrc[pos] = src[e];
        rw[pos]   = w[e];
    }
}

// ---------------------------------------------------------------------------
__global__ __launch_bounds__(256) void f32_to_bf16_kernel(
    const float* __restrict__ in, __bf16* __restrict__ out, int n8)
{
    for (int i = blockIdx.x * blockDim.x + threadIdx.x; i < n8; i += gridDim.x * blockDim.x) {
        float4 a = *reinterpret_cast<const float4*>(in + (size_t)i * 8);
        float4 b = *reinterpret_cast<const float4*>(in + (size_t)i * 8 + 4);
        bf16x8 v;
        v[0] = (__bf16)a.x; v[1] = (__bf16)a.y; v[2] = (__bf16)a.z; v[3] = (__bf16)a.w;
        v[4] = (__bf16)b.x; v[5] = (__bf16)b.y; v[6] = (__bf16)b.z; v[7] = (__bf16)b.w;
        *reinterpret_cast<bf16x8*>(out + (size_t)i * 8) = v;
    }
}

// WcatT[n][k] bf16 [256][512]: k<256 -> Wl[k][n], k>=256 -> Wr[k-256][n]
__global__ __launch_bounds__(256) void wtrans_kernel(
    const float* __restrict__ Wl, const float* __restrict__ Wr, __bf16* __restrict__ out)
{
    int t = blockIdx.x * blockDim.x + threadIdx.x;
    if (t >= 256 * 512) return;
    int n = t >> 9;
    int k = t & 511;
    float v = (k < 256) ? Wl[(size_t)k * 256 + n] : Wr[(size_t)(k - 256) * 256 + n];
    out[t] = (__bf16)v;
}

// ---------------------------------------------------------------------------
// Aggregation: one wave per dst row; 2 edges per wave-step (32 lanes x 16B),
// 16 edges in flight; cross-half combine via shfl_xor(32).   (unchanged R3)
// ---------------------------------------------------------------------------
__global__ __launch_bounds__(256) void aggregate_bf16(
    const __bf16* __restrict__ xsrc, const int* __restrict__ rsrc,
    const float* __restrict__ rw, const int* __restrict__ rowptr,
    __bf16* __restrict__ mean, int ndst)
{
    int wid  = (blockIdx.x * blockDim.x + threadIdx.x) >> 6;
    int lane = threadIdx.x & 63;
    if (wid >= ndst) return;
    int beg = rowptr[wid], end = rowptr[wid + 1];
    const int half = lane >> 5, hl = lane & 31;
    const __bf16* xcol = xsrc + hl * 8;
    float acc[8];
    #pragma unroll
    for (int i = 0; i < 8; ++i) acc[i] = 0.f;

    int j0 = beg;
    while (j0 < end) {
        int m = end - j0; if (m > 64) m = 64;
        int   sl = (lane < m) ? rsrc[j0 + lane] : 0;
        float wl = (lane < m) ? rw[j0 + lane]   : 0.f;
        int t = 0;
        for (; t + 16 <= m; t += 16) {
            bf16x8 v[8]; float wt[8];
            #pragma unroll
            for (int u = 0; u < 8; ++u) {
                int tt = t + u * 2;
                int e0 = __builtin_amdgcn_readlane(sl, tt);
                int e1 = __builtin_amdgcn_readlane(sl, tt + 1);
                int w0 = __builtin_amdgcn_readlane(__float_as_int(wl), tt);
                int w1 = __builtin_amdgcn_readlane(__float_as_int(wl), tt + 1);
                int s = half ? e1 : e0;
                wt[u] = __int_as_float(half ? w1 : w0);
                v[u] = *reinterpret_cast<const bf16x8*>(xcol + (size_t)s * DFEAT);
            }
            #pragma unroll
            for (int u = 0; u < 8; ++u)
                #pragma unroll
                for (int i = 0; i < 8; ++i) acc[i] += wt[u] * (float)v[u][i];
        }
        for (; t < m; t += 2) {
            int e0 = __builtin_amdgcn_readlane(sl, t);
            int e1 = __builtin_amdgcn_readlane(sl, (t + 1 < 64) ? t + 1 : 63);
            int w0 = __builtin_amdgcn_readlane(__float_as_int(wl), t);
            int w1 = __builtin_amdgcn_readlane(__float_as_int(wl), (t + 1 < 64) ? t + 1 : 63);
            int s = half ? e1 : e0;
            float wv2 = __int_as_float(half ? w1 : w0);
            if (half && t + 1 >= m) wv2 = 0.f;
            bf16x8 v = *reinterpret_cast<const bf16x8*>(xcol + (size_t)s * DFEAT);
            #pragma unroll
            for (int i = 0; i < 8; ++i) acc[i] += wv2 * (float)v[i];
        }
        j0 += m;
    }

    #pragma unroll
    for (int i = 0; i < 8; ++i) acc[i] += __shfl_xor(acc[i], 32);
    float inv = (end > beg) ? 1.0f / (float)(end - beg) : 0.0f;
    if (half == 0) {
        bf16x8 o;
        #pragma unroll
        for (int i = 0; i < 8; ++i) o[i] = (__bf16)(acc[i] * inv);
        *reinterpret_cast<bf16x8*>(mean + (size_t)wid * DFEAT + hl * 8) = o;
    }
}

// ---------------------------------------------------------------------------
// Pipelined MFMA GEMM, low-LDS variant: out[i,:] = epi(A@Wl + B@Wr + bias)
// 256 thr = 4 waves; wave w owns cols [w*64, w*64+64); BM=64 rows/block.
// K=512 as 8 chunks of BK=64 (chunks 0-3 read Amat, 4-7 read Bmat).
// A only in LDS (double-buffered 2x8KB -> multiple blocks/CU for implicit
// cross-block latency hiding); B (weights, 256KB L2-hot) loaded per-chunk
// straight to registers. T2 XOR swizzle on A staging + reads.
// ---------------------------------------------------------------------------
template<int EPI>
__global__ __launch_bounds__(256) void gemm_mfma(
    const __bf16* __restrict__ Amat, const __bf16* __restrict__ Bmat,
    const __bf16* __restrict__ WT, const float* __restrict__ bias,
    const __bf16* __restrict__ resid, void* __restrict__ outv, int n)
{
    __shared__ char sA[2][64 * 128];      // [64 rows][64 k] bf16, dbuf = 16 KB

    const int tid  = threadIdx.x;
    const int lane = tid & 63;
    const int wv   = tid >> 6;            // wave = col group
    const int lo   = lane & 15;
    const int hi   = lane >> 4;
    const int brow = blockIdx.x * 64;
    const int wcol = wv * 64;
    const int nm1  = n - 1;

    f32x4 acc[4][4];
    #pragma unroll
    for (int i = 0; i < 4; ++i)
        #pragma unroll
        for (int j = 0; j < 4; ++j) acc[i][j] = (f32x4){0.f, 0.f, 0.f, 0.f};

    auto stage = [&](int chunk, int buf) {
        const __bf16* mat = (chunk < 4) ? Amat : Bmat;
        const int kbyte = (chunk & 3) * 128;
        #pragma unroll
        for (int q = 0; q < 2; ++q) {          // 512 slots of 16B, 2/thread
            int s = q * 256 + tid;
            int r = s >> 3, sub = s & 7;
            int grow = brow + r; if (grow > nm1) grow = nm1;
            int srcoff = (sub * 16) ^ ((r & 7) << 4);
            const char* g = reinterpret_cast<const char*>(mat) + (size_t)grow * 512 + kbyte + srcoff;
            __builtin_amdgcn_global_load_lds(
                (const __attribute__((address_space(1))) void*)g,
                (__attribute__((address_space(3))) void*)(sA[buf] + s * 16), 16, 0, 0);
        }
    };

    stage(0, 0);
    __syncthreads();

    for (int c = 0; c < 8; ++c) {
        const int cur = c & 1;
        if (c < 7) stage(c + 1, cur ^ 1);
        // B fragments for this chunk straight from L2 (WT row stride = 512 elem)
        bf16x8 bfr[2][4];
        #pragma unroll
        for (int ks = 0; ks < 2; ++ks)
            #pragma unroll
            for (int nn = 0; nn < 4; ++nn)
                bfr[ks][nn] = *reinterpret_cast<const bf16x8*>(
                    WT + (size_t)(wcol + nn * 16 + lo) * 512 + c * 64 + ks * 32 + hi * 8);
        #pragma unroll
        for (int ks = 0; ks < 2; ++ks) {
            const int kb = ks * 64 + hi * 16;
            #pragma unroll
            for (int mm = 0; mm < 4; ++mm) {
                int r = mm * 16 + lo;
                bf16x8 a = *reinterpret_cast<const bf16x8*>(
                    sA[cur] + r * 128 + (kb ^ ((r & 7) << 4)));
                #pragma unroll
                for (int nn = 0; nn < 4; ++nn)
                    acc[mm][nn] = __builtin_amdgcn_mfma_f32_16x16x32_bf16(
                        a, bfr[ks][nn], acc[mm][nn], 0, 0, 0);
            }
        }
        __syncthreads();   // drains vmcnt (next chunk staged) + lgkm
    }

    // epilogue: D col = lane&15, row = (lane>>4)*4 + reg
    #pragma unroll
    for (int mm = 0; mm < 4; ++mm) {
        #pragma unroll
        for (int nn = 0; nn < 4; ++nn) {
            int col = wcol + nn * 16 + lo;
            float bv = bias[col];
            #pragma unroll
            for (int r = 0; r < 4; ++r) {
                int grow = brow + mm * 16 + hi * 4 + r;
                if (grow >= n) continue;
                float v = acc[mm][nn][r] + bv;
                if (EPI == 1) {
                    float rv = (float)resid[(size_t)grow * DFEAT + col];
                    ((__bf16*)outv)[(size_t)grow * DFEAT + col] =
                        (__bf16)(rv + fmaxf(v, 0.f));
                } else {
                    ((float*)outv)[(size_t)grow * DFEAT + col] = v;
                }
            }
        }
    }
}

// ---------------------------------------------------------------------------
extern "C" void kernel_launch(void* const* d_in, const int* in_sizes, int n_in,
                              void* d_out, int out_size, void* d_ws, size_t ws_size,
                              hipStream_t stream) {
    const float* x_user  = (const float*)d_in[0];
    const float* x_movie = (const float*)d_in[1];
    const int*   src_um  = (const int*)d_in[2];
    const int*   dst_um  = (const int*)d_in[3];
    const float* w_um    = (const float*)d_in[4];
    const int*   src_mu  = (const int*)d_in[5];
    const int*   dst_mu  = (const int*)d_in[6];
    const float* w_mu    = (const float*)d_in[7];
    const float* c1_um_Wl = (const float*)d_in[8];
    const float* c1_um_Wr = (const float*)d_in[9];
    const float* c1_um_b  = (const float*)d_in[10];
    const float* c1_mu_Wl = (const float*)d_in[11];
    const float* c1_mu_Wr = (const float*)d_in[12];
    const float* c1_mu_b  = (const float*)d_in[13];
    const float* c2_um_Wl = (const float*)d_in[14];
    const float* c2_um_Wr = (const float*)d_in[15];
    const float* c2_um_b  = (const float*)d_in[16];
    const float* c2_mu_Wl = (const float*)d_in[17];
    const float* c2_mu_Wr = (const float*)d_in[18];
    const float* c2_mu_b  = (const float*)d_in[19];

    const int NU = in_sizes[0] / DFEAT;
    const int NM = in_sizes[1] / DFEAT;
    const int E_um = in_sizes[2];
    const int E_mu = in_sizes[5];

    char* p = (char*)d_ws;
    auto carve = [&](size_t bytes) { char* r = p; p += (bytes + 255) & ~(size_t)255; return r; };
    int* rowptr_m = (int*)carve((size_t)(NM + 1) * 4);
    int* rowptr_u = (int*)carve((size_t)(NU + 1) * 4);
    int* cursor_m = (int*)carve((size_t)NM * 4);
    int* cursor_u = (int*)carve((size_t)NU * 4);
    int* bsum_m   = (int*)carve(64 * 4);
    int* bsum_u   = (int*)carve(64 * 4);
    __bf16* xu_bf = (__bf16*)carve((size_t)NU * DFEAT * 2);
    __bf16* xm_bf = (__bf16*)carve((size_t)NM * DFEAT * 2);
    __bf16* ru_bf = (__bf16*)carve((size_t)NU * DFEAT * 2);
    __bf16* rm_bf = (__bf16*)carve((size_t)NM * DFEAT * 2);
    __bf16* wt_c1um = (__bf16*)carve(256 * 512 * 2);
    __bf16* wt_c1mu = (__bf16*)carve(256 * 512 * 2);
    __bf16* wt_c2um = (__bf16*)carve(256 * 512 * 2);
    __bf16* wt_c2mu = (__bf16*)carve(256 * 512 * 2);

    char* dtail = (char*)d_out + (size_t)(NU + NM) * DFEAT * 2;
    int*   rsrc_m = (int*)  (dtail);
    float* rw_m   = (float*)(dtail + (size_t)E_um * 4);
    int*   rsrc_u = (int*)  (dtail + (size_t)E_um * 8);
    float* rw_u   = (float*)(dtail + (size_t)E_um * 8 + (size_t)E_mu * 4);

    __bf16* mean1_u = (__bf16*)d_out;
    __bf16* mean1_m = (__bf16*)d_out + (size_t)NU * DFEAT;
    float* out_user  = (float*)d_out;
    float* out_movie = (float*)d_out + (size_t)NU * DFEAT;

    // ---- CSR build ----
    hipMemsetAsync(rowptr_m, 0, (size_t)(NM + 1) * 4, stream);
    hipMemsetAsync(rowptr_u, 0, (size_t)(NU + 1) * 4, stream);
    hist_kernel<<<2048, 256, 0, stream>>>(dst_um, E_um, rowptr_m);
    hist_kernel<<<2048, 256, 0, stream>>>(dst_mu, E_mu, rowptr_u);
    const int nbM = (NM + 1 + 2047) / 2048;
    const int nbU = (NU + 1 + 2047) / 2048;
    scan_block<<<nbM, 256, 0, stream>>>(rowptr_m, NM + 1, bsum_m);
    scan_block<<<nbU, 256, 0, stream>>>(rowptr_u, NU + 1, bsum_u);
    scan_sums<<<1, 64, 0, stream>>>(bsum_m, nbM);
    scan_sums<<<1, 64, 0, stream>>>(bsum_u, nbU);
    scan_add<<<nbM, 256, 0, stream>>>(rowptr_m, NM + 1, bsum_m);
    scan_add<<<nbU, 256, 0, stream>>>(rowptr_u, NU + 1, bsum_u);
    copy_int<<<256, 256, 0, stream>>>(rowptr_m, cursor_m, NM);
    copy_int<<<256, 256, 0, stream>>>(rowptr_u, cursor_u, NU);
    fill_kernel<<<2048, 256, 0, stream>>>(dst_um, src_um, w_um, E_um, cursor_m, rsrc_m, rw_m);
    fill_kernel<<<2048, 256, 0, stream>>>(dst_mu, src_mu, w_mu, E_mu, cursor_u, rsrc_u, rw_u);

    // ---- bf16 features + transposed weights ----
    f32_to_bf16_kernel<<<2048, 256, 0, stream>>>(x_user, xu_bf, NU * DFEAT / 8);
    f32_to_bf16_kernel<<<2048, 256, 0, stream>>>(x_movie, xm_bf, NM * DFEAT / 8);
    wtrans_kernel<<<512, 256, 0, stream>>>(c1_um_Wl, c1_um_Wr, wt_c1um);
    wtrans_kernel<<<512, 256, 0, stream>>>(c1_mu_Wl, c1_mu_Wr, wt_c1mu);
    wtrans_kernel<<<512, 256, 0, stream>>>(c2_um_Wl, c2_um_Wr, wt_c2um);
    wtrans_kernel<<<512, 256, 0, stream>>>(c2_mu_Wl, c2_mu_Wr, wt_c2mu);

    // ---- layer 1 ----
    aggregate_bf16<<<(NM + 3) / 4, 256, 0, stream>>>(xu_bf, rsrc_m, rw_m, rowptr_m, mean1_m, NM);
    aggregate_bf16<<<(NU + 3) / 4, 256, 0, stream>>>(xm_bf, rsrc_u, rw_u, rowptr_u, mean1_u, NU);
    gemm_mfma<1><<<(NM + 63) / 64, 256, 0, stream>>>(mean1_m, xm_bf, wt_c1um, c1_um_b, xm_bf, rm_bf, NM);
    gemm_mfma<1><<<(NU + 63) / 64, 256, 0, stream>>>(mean1_u, xu_bf, wt_c1mu, c1_mu_b, xu_bf, ru_bf, NU);

    // ---- layer 2 ----
    __bf16* mean2_m = xm_bf;
    __bf16* mean2_u = xu_bf;
    aggregate_bf16<<<(NM + 3) / 4, 256, 0, stream>>>(ru_bf, rsrc_m, rw_m, rowptr_m, mean2_m, NM);
    aggregate_bf16<<<(NU + 3) / 4, 256, 0, stream>>>(rm_bf, rsrc_u, rw_u, rowptr_u, mean2_u, NU);
    gemm_mfma<0><<<(NM + 63) / 64, 256, 0, stream>>>(mean2_m, rm_bf, wt_c2um, c2_um_b, nullptr, out_movie, NM);
    gemm_mfma<0><<<(NU + 63) / 64, 256, 0, stream>>>(mean2_u, ru_bf, wt_c2mu, c2_mu_b, nullptr, out_user, NU);
}